// Round 1
// baseline (930.509 us; speedup 1.0000x reference)
//
#include <hip/hip_runtime.h>
#include <math.h>

#define C 128

// ---------------- gcn_norm ----------------

__global__ void k_init_dis(float* __restrict__ dis, int n) {
    int i = blockIdx.x * blockDim.x + threadIdx.x;
    if (i < n) dis[i] = 1.0f;  // self-loop contributes 1 to degree
}

__global__ void k_deg(const int* __restrict__ dst, float* __restrict__ dis, int e) {
    int i = blockIdx.x * blockDim.x + threadIdx.x;
    if (i < e) atomicAdd(&dis[dst[i]], 1.0f);
}

__global__ void k_finalize_dis(float* __restrict__ dis, int n) {
    int i = blockIdx.x * blockDim.x + threadIdx.x;
    if (i < n) dis[i] = rsqrtf(dis[i]);  // deg >= 1 always (self loops)
}

__global__ void k_edge_w(const int* __restrict__ src, const int* __restrict__ dst,
                         const float* __restrict__ ew, const float* __restrict__ dis,
                         float* __restrict__ w, int e) {
    int i = blockIdx.x * blockDim.x + threadIdx.x;
    if (i < e) w[i] = dis[src[i]] * ew[i] * dis[dst[i]];
}

// ---------------- GEMM: Y[n,128] = X[n,128] @ W[128,128] ----------------
// 8 rows per block, 256 threads = 128 cols x 2 row-halves, x tile in LDS.

__global__ __launch_bounds__(256) void k_gemm(const float* __restrict__ X,
                                              const float* __restrict__ W,
                                              float* __restrict__ Y, int n) {
    __shared__ float xs[8][C];
    const int base = blockIdx.x * 8;
    const int tid = threadIdx.x;

    for (int t = tid; t < 8 * C; t += 256) {
        int r = t >> 7, c = t & 127;
        int row = base + r;
        xs[r][c] = (row < n) ? X[row * C + c] : 0.0f;
    }
    __syncthreads();

    const int c = tid & 127;
    const int rh = tid >> 7;
    for (int rr = 0; rr < 4; ++rr) {
        int r = rr * 2 + rh;
        int row = base + r;
        if (row >= n) continue;
        float acc = 0.0f;
        #pragma unroll 16
        for (int k = 0; k < C; ++k) {
            acc += xs[r][k] * W[k * C + c];
        }
        Y[row * C + c] = acc;
    }
}

// ---------------- aggregation ----------------
// Out[i,c] = bias[c] + dis[i]^2 * H[i,c]   (self loop, ew=1)
__global__ void k_init_agg(const float* __restrict__ H, const float* __restrict__ dis,
                           const float* __restrict__ bias, float* __restrict__ Out, int n) {
    int idx = blockIdx.x * blockDim.x + threadIdx.x;
    if (idx >= n * C) return;
    int row = idx >> 7, c = idx & 127;
    float d = dis[row];
    Out[idx] = bias[c] + d * d * H[idx];
}

// Out[dst,c] += w[e] * H[src,c] for each edge, 128 lanes per edge (2 edges/block)
__global__ __launch_bounds__(256) void k_scatter(const int* __restrict__ src,
                                                 const int* __restrict__ dst,
                                                 const float* __restrict__ w,
                                                 const float* __restrict__ H,
                                                 float* __restrict__ Out, int e) {
    int eidx = blockIdx.x * 2 + (threadIdx.x >> 7);
    if (eidx >= e) return;
    int c = threadIdx.x & 127;
    int s = src[eidx];
    int d = dst[eidx];
    float we = w[eidx];
    atomicAdd(&Out[d * C + c], we * H[s * C + c]);
}

// ---------------- LayerNorm + exact GELU (+ optional residual), in place ----------------
// one 64-lane wave per row, 2 elements per lane; block = 4 rows.
__global__ __launch_bounds__(256) void k_ln_gelu(float* __restrict__ Y,
                                                 const float* __restrict__ g,
                                                 const float* __restrict__ beta,
                                                 const float* __restrict__ resid,
                                                 int n) {
    int row = blockIdx.x * 4 + (threadIdx.x >> 6);
    if (row >= n) return;
    int lane = threadIdx.x & 63;

    float* yrow = Y + row * C;
    float y0 = yrow[lane];
    float y1 = yrow[lane + 64];

    float s = y0 + y1;
    float sq = y0 * y0 + y1 * y1;
    #pragma unroll
    for (int off = 32; off >= 1; off >>= 1) {
        s  += __shfl_xor(s, off, 64);
        sq += __shfl_xor(sq, off, 64);
    }
    float mu = s * (1.0f / C);
    float var = sq * (1.0f / C) - mu * mu;
    float rstd = rsqrtf(var + 1e-5f);

    float t0 = (y0 - mu) * rstd * g[lane] + beta[lane];
    float t1 = (y1 - mu) * rstd * g[lane + 64] + beta[lane + 64];
    // exact gelu: x * 0.5 * (1 + erf(x/sqrt(2)))
    t0 = 0.5f * t0 * (1.0f + erff(t0 * 0.70710678118654752f));
    t1 = 0.5f * t1 * (1.0f + erff(t1 * 0.70710678118654752f));

    if (resid != nullptr) {
        t0 += resid[row * C + lane];
        t1 += resid[row * C + lane + 64];
    }
    yrow[lane] = t0;
    yrow[lane + 64] = t1;
}

// ---------------- launch ----------------

extern "C" void kernel_launch(void* const* d_in, const int* in_sizes, int n_in,
                              void* d_out, int out_size, void* d_ws, size_t ws_size,
                              hipStream_t stream) {
    const float* x      = (const float*)d_in[0];
    const int*   eidx   = (const int*)d_in[1];
    const float* ew     = (const float*)d_in[2];
    const float* W1     = (const float*)d_in[3];
    const float* b1     = (const float*)d_in[4];
    const float* g1     = (const float*)d_in[5];
    const float* beta1  = (const float*)d_in[6];
    const float* W2     = (const float*)d_in[7];
    const float* b2     = (const float*)d_in[8];
    const float* g2     = (const float*)d_in[9];
    const float* beta2  = (const float*)d_in[10];

    const int n = in_sizes[0] / C;
    const int e = in_sizes[2];
    const int* src = eidx;
    const int* dst = eidx + e;

    float* out = (float*)d_out;

    float* dis  = (float*)d_ws;          // n floats
    float* w    = dis + n;               // e floats
    float* buf1 = w + e;                 // n*C floats (GEMM output)

    const int B = 256;

    // gcn_norm
    k_init_dis<<<(n + B - 1) / B, B, 0, stream>>>(dis, n);
    k_deg<<<(e + B - 1) / B, B, 0, stream>>>(dst, dis, e);
    k_finalize_dis<<<(n + B - 1) / B, B, 0, stream>>>(dis, n);
    k_edge_w<<<(e + B - 1) / B, B, 0, stream>>>(src, dst, ew, dis, w, e);

    // ---- layer 1 ----
    k_gemm<<<(n + 7) / 8, B, 0, stream>>>(x, W1, buf1, n);
    k_init_agg<<<(n * C + B - 1) / B, B, 0, stream>>>(buf1, dis, b1, out, n);
    k_scatter<<<(e + 1) / 2, B, 0, stream>>>(src, dst, w, buf1, out, e);
    k_ln_gelu<<<(n + 3) / 4, B, 0, stream>>>(out, g1, beta1, nullptr, n);

    // ---- layer 2 ---- (out currently holds h_act; GEMM2 consumes it, then out is reused)
    k_gemm<<<(n + 7) / 8, B, 0, stream>>>(out, W2, buf1, n);
    k_init_agg<<<(n * C + B - 1) / B, B, 0, stream>>>(buf1, dis, b2, out, n);
    k_scatter<<<(e + 1) / 2, B, 0, stream>>>(src, dst, w, buf1, out, e);
    k_ln_gelu<<<(n + 3) / 4, B, 0, stream>>>(out, g2, beta2, x, n);
}

// Round 2
// 597.998 us; speedup vs baseline: 1.5560x; 1.5560x over previous
//
#include <hip/hip_runtime.h>
#include <math.h>

#define C 128

typedef __attribute__((ext_vector_type(8))) short short8;
typedef __attribute__((ext_vector_type(4))) float f32x4;
typedef __attribute__((ext_vector_type(4))) unsigned short ushort4_t;

__device__ inline unsigned short f2b(float f) {
    union { float f; unsigned int u; } v; v.f = f;
    unsigned int u = v.u;
    return (unsigned short)((u + 0x7FFFu + ((u >> 16) & 1u)) >> 16);  // RNE
}

// ---------------- gcn_norm ----------------

__global__ void k_init_dis(float* __restrict__ dis, int n) {
    int i = blockIdx.x * blockDim.x + threadIdx.x;
    if (i < n) dis[i] = 1.0f;  // self-loop contributes 1 to degree
}

__global__ void k_deg(const int* __restrict__ dst, float* __restrict__ dis, int e) {
    int i = blockIdx.x * blockDim.x + threadIdx.x;
    if (i < e) atomicAdd(&dis[dst[i]], 1.0f);
}

__global__ void k_finalize_dis(float* __restrict__ dis, int n) {
    int i = blockIdx.x * blockDim.x + threadIdx.x;
    if (i < n) dis[i] = rsqrtf(dis[i]);  // deg >= 1 always (self loops)
}

__global__ void k_edge_w(const int* __restrict__ src, const int* __restrict__ dst,
                         const float* __restrict__ ew, const float* __restrict__ dis,
                         float* __restrict__ w, int e) {
    int i = blockIdx.x * blockDim.x + threadIdx.x;
    if (i < e) w[i] = dis[src[i]] * ew[i] * dis[dst[i]];
}

// ---------------- W pack: f32 [128][128] -> bf16 fragment layout ----------------
// Wp[((ct*4+ks)*64 + lane)*8 + j] = bf16(W[k][c]),
//   k = ks*32 + (lane>>4)*8 + j, c = ct*16 + (lane&15)
__global__ void k_pack_w(const float* __restrict__ W, unsigned short* __restrict__ Wp) {
    int p = blockIdx.x * blockDim.x + threadIdx.x;
    if (p >= C * C) return;
    int j = p & 7;
    int l = (p >> 3) & 63;
    int t = p >> 9;           // ct*4 + ks
    int ks = t & 3, ct = t >> 2;
    int k = ks * 32 + ((l >> 4) << 3) + j;
    int c = (ct << 4) + (l & 15);
    Wp[p] = f2b(W[k * C + c]);
}

// ---------------- MFMA GEMM: H[n,128] = bf16(X[n,128]) @ Wp ----------------
// 32 rows/block, 256 threads = 4 waves in a 2x2 (16-row x 64-col) layout.
// If OutInit != nullptr also writes OutInit = bias + dis^2 * H (fused init_agg).
__global__ __launch_bounds__(256) void k_gemm_mfma(
    const float* __restrict__ X, const unsigned short* __restrict__ Wp,
    const float* __restrict__ dis, const float* __restrict__ bias,
    float* __restrict__ H, float* __restrict__ OutInit, int n) {
    __shared__ unsigned short xs[32 * C];  // 8 KB, XOR-swizzled
    const int tid = threadIdx.x;
    const int base = blockIdx.x * 32;

    // stage X -> LDS (bf16), swizzle byte ^= (row&7)<<4
    const float4* Xv = (const float4*)(X + (size_t)base * C);
    #pragma unroll
    for (int i = 0; i < 4; ++i) {
        int idx4 = i * 256 + tid;        // 0..1023 float4s in 32x128 tile
        int elem = idx4 * 4;
        int r = elem >> 7, c = elem & 127;
        float4 v = make_float4(0.f, 0.f, 0.f, 0.f);
        if (base + r < n) v = Xv[idx4];
        ushort4_t pkt;
        pkt.x = f2b(v.x); pkt.y = f2b(v.y); pkt.z = f2b(v.z); pkt.w = f2b(v.w);
        int byte = (r * 256 + c * 2) ^ ((r & 7) << 4);
        *(ushort4_t*)((char*)xs + byte) = pkt;
    }
    __syncthreads();

    const int lane = tid & 63;
    const int wid = tid >> 6;
    const int wm = wid >> 1;              // 0..1 (row half)
    const int wn = wid & 1;               // 0..1 (col half)
    const int arow = wm * 16 + (lane & 15);
    const int kg = lane >> 4;

    f32x4 acc[4] = {f32x4{0,0,0,0}, f32x4{0,0,0,0}, f32x4{0,0,0,0}, f32x4{0,0,0,0}};

    #pragma unroll
    for (int ks = 0; ks < 4; ++ks) {
        int abyte = (arow * 256 + ks * 64 + kg * 16) ^ ((arow & 7) << 4);
        short8 a = *(const short8*)((const char*)xs + abyte);
        #pragma unroll
        for (int nt = 0; nt < 4; ++nt) {
            int ct = wn * 4 + nt;
            short8 b = *(const short8*)(Wp + (size_t)((ct * 4 + ks) * 64 + lane) * 8);
            acc[nt] = __builtin_amdgcn_mfma_f32_16x16x32_bf16(a, b, acc[nt], 0, 0, 0);
        }
    }

    // epilogue: C/D mapping col = lane&15, row = kg*4 + reg
    const int rbase = base + wm * 16 + kg * 4;
    float d2[4] = {0.f, 0.f, 0.f, 0.f};
    if (OutInit) {
        #pragma unroll
        for (int r = 0; r < 4; ++r) {
            int row = rbase + r;
            if (row < n) { float d = dis[row]; d2[r] = d * d; }
        }
    }
    #pragma unroll
    for (int nt = 0; nt < 4; ++nt) {
        int col = wn * 64 + nt * 16 + (lane & 15);
        float bs = OutInit ? bias[col] : 0.f;
        #pragma unroll
        for (int r = 0; r < 4; ++r) {
            int row = rbase + r;
            if (row >= n) continue;
            float v = acc[nt][r];
            H[(size_t)row * C + col] = v;
            if (OutInit) OutInit[(size_t)row * C + col] = bs + d2[r] * v;
        }
    }
}

// ---------------- aggregation ----------------
// Out[i,c] = bias[c] + dis[i]^2 * H[i,c]   (self loop, ew=1)
__global__ void k_init_agg(const float* __restrict__ H, const float* __restrict__ dis,
                           const float* __restrict__ bias, float* __restrict__ Out, int n) {
    int idx = blockIdx.x * blockDim.x + threadIdx.x;
    if (idx >= n * C) return;
    int row = idx >> 7, c = idx & 127;
    float d = dis[row];
    Out[idx] = bias[c] + d * d * H[idx];
}

// Out[dst,c] += w[e] * H[src,c], 128 lanes per edge (2 edges/block)
__global__ __launch_bounds__(256) void k_scatter(const int* __restrict__ src,
                                                 const int* __restrict__ dst,
                                                 const float* __restrict__ w,
                                                 const float* __restrict__ H,
                                                 float* __restrict__ Out, int e) {
    int eidx = blockIdx.x * 2 + (threadIdx.x >> 7);
    if (eidx >= e) return;
    int c = threadIdx.x & 127;
    int s = src[eidx];
    int d = dst[eidx];
    float we = w[eidx];
    atomicAdd(&Out[(size_t)d * C + c], we * H[(size_t)s * C + c]);
}

// ---------------- LayerNorm + exact GELU (+ optional residual), in place ----------------
__global__ __launch_bounds__(256) void k_ln_gelu(float* __restrict__ Y,
                                                 const float* __restrict__ g,
                                                 const float* __restrict__ beta,
                                                 const float* __restrict__ resid,
                                                 int n) {
    int row = blockIdx.x * 4 + (threadIdx.x >> 6);
    if (row >= n) return;
    int lane = threadIdx.x & 63;

    float* yrow = Y + (size_t)row * C;
    float y0 = yrow[lane];
    float y1 = yrow[lane + 64];

    float s = y0 + y1;
    float sq = y0 * y0 + y1 * y1;
    #pragma unroll
    for (int off = 32; off >= 1; off >>= 1) {
        s  += __shfl_xor(s, off, 64);
        sq += __shfl_xor(sq, off, 64);
    }
    float mu = s * (1.0f / C);
    float var = sq * (1.0f / C) - mu * mu;
    float rstd = rsqrtf(var + 1e-5f);

    float t0 = (y0 - mu) * rstd * g[lane] + beta[lane];
    float t1 = (y1 - mu) * rstd * g[lane + 64] + beta[lane + 64];
    t0 = 0.5f * t0 * (1.0f + erff(t0 * 0.70710678118654752f));
    t1 = 0.5f * t1 * (1.0f + erff(t1 * 0.70710678118654752f));

    if (resid != nullptr) {
        t0 += resid[(size_t)row * C + lane];
        t1 += resid[(size_t)row * C + lane + 64];
    }
    yrow[lane] = t0;
    yrow[lane + 64] = t1;
}

// ---------------- launch ----------------

extern "C" void kernel_launch(void* const* d_in, const int* in_sizes, int n_in,
                              void* d_out, int out_size, void* d_ws, size_t ws_size,
                              hipStream_t stream) {
    const float* x      = (const float*)d_in[0];
    const int*   eidx   = (const int*)d_in[1];
    const float* ew     = (const float*)d_in[2];
    const float* W1     = (const float*)d_in[3];
    const float* b1     = (const float*)d_in[4];
    const float* g1     = (const float*)d_in[5];
    const float* beta1  = (const float*)d_in[6];
    const float* W2     = (const float*)d_in[7];
    const float* b2     = (const float*)d_in[8];
    const float* g2     = (const float*)d_in[9];
    const float* beta2  = (const float*)d_in[10];

    const int n = in_sizes[0] / C;
    const int e = in_sizes[2];
    const int* src = eidx;
    const int* dst = eidx + e;

    float* out = (float*)d_out;

    float* dis  = (float*)d_ws;              // n floats
    float* w    = dis + n;                   // e floats
    float* buf1 = w + e;                     // n*C floats (GEMM output H)
    unsigned short* W1p = (unsigned short*)(buf1 + (size_t)n * C);  // 16384 u16
    unsigned short* W2p = W1p + C * C;                              // 16384 u16

    const int B = 256;

    // gcn_norm
    k_init_dis<<<(n + B - 1) / B, B, 0, stream>>>(dis, n);
    k_deg<<<(e + B - 1) / B, B, 0, stream>>>(dst, dis, e);
    k_finalize_dis<<<(n + B - 1) / B, B, 0, stream>>>(dis, n);
    k_edge_w<<<(e + B - 1) / B, B, 0, stream>>>(src, dst, ew, dis, w, e);

    // pack weights to MFMA fragment layout (bf16)
    k_pack_w<<<(C * C + B - 1) / B, B, 0, stream>>>(W1, W1p);
    k_pack_w<<<(C * C + B - 1) / B, B, 0, stream>>>(W2, W2p);

    // ---- layer 1 ---- (GEMM fuses init_agg: out = b1 + dis^2 * H)
    k_gemm_mfma<<<(n + 31) / 32, B, 0, stream>>>(x, W1p, dis, b1, buf1, out, n);
    k_scatter<<<(e + 1) / 2, B, 0, stream>>>(src, dst, w, buf1, out, e);
    k_ln_gelu<<<(n + 3) / 4, B, 0, stream>>>(out, g1, beta1, nullptr, n);

    // ---- layer 2 ---- (GEMM reads out -> cannot fuse init into out; separate init_agg)
    k_gemm_mfma<<<(n + 31) / 32, B, 0, stream>>>(out, W2p, dis, b2, buf1, nullptr, n);
    k_init_agg<<<(n * C + B - 1) / B, B, 0, stream>>>(buf1, dis, b2, out, n);
    k_scatter<<<(e + 1) / 2, B, 0, stream>>>(src, dst, w, buf1, out, e);
    k_ln_gelu<<<(n + 3) / 4, B, 0, stream>>>(out, g2, beta2, x, n);
}

// Round 3
// 270.374 us; speedup vs baseline: 3.4416x; 2.2117x over previous
//
#include <hip/hip_runtime.h>
#include <math.h>

#define C 128

typedef __attribute__((ext_vector_type(8))) short short8;
typedef __attribute__((ext_vector_type(4))) float f32x4;
typedef __attribute__((ext_vector_type(4))) unsigned short ushort4_t;

__device__ inline unsigned short f2b(float f) {
    union { float f; unsigned int u; } v; v.f = f;
    unsigned int u = v.u;
    return (unsigned short)((u + 0x7FFFu + ((u >> 16) & 1u)) >> 16);  // RNE
}

// ---------------- gcn_norm + CSR build ----------------

__global__ void k_zero(int* __restrict__ cnt, int* __restrict__ cursor, int n) {
    int i = blockIdx.x * blockDim.x + threadIdx.x;
    if (i < n) cnt[i] = 0;
    if (i == 0) *cursor = 0;
}

__global__ void k_cnt(const int* __restrict__ dst, int* __restrict__ cnt, int e) {
    int i = blockIdx.x * blockDim.x + threadIdx.x;
    if (i < e) atomicAdd(&cnt[dst[i]], 1);
}

__global__ void k_finalize_dis(const int* __restrict__ cnt, float* __restrict__ dis, int n) {
    int i = blockIdx.x * blockDim.x + threadIdx.x;
    if (i < n) dis[i] = rsqrtf((float)cnt[i] + 1.0f);  // +1 self loop
}

__global__ void k_reserve(const int* __restrict__ cnt, int* __restrict__ rowbeg,
                          int* __restrict__ rowcur, int* __restrict__ cursor, int n) {
    int i = blockIdx.x * blockDim.x + threadIdx.x;
    if (i < n) {
        int b = atomicAdd(cursor, cnt[i]);
        rowbeg[i] = b;
        rowcur[i] = b;
    }
}

// place edge into its dst segment; also computes normalized weight
__global__ void k_place(const int* __restrict__ src, const int* __restrict__ dst,
                        const float* __restrict__ ew, const float* __restrict__ dis,
                        int* __restrict__ rowcur, int* __restrict__ esrc,
                        float* __restrict__ ews, int e) {
    int i = blockIdx.x * blockDim.x + threadIdx.x;
    if (i >= e) return;
    int s = src[i], d = dst[i];
    int p = atomicAdd(&rowcur[d], 1);
    esrc[p] = s;
    ews[p] = dis[s] * ew[i] * dis[d];
}

// ---------------- W pack: f32 [128][128] -> bf16 fragment layout ----------------
__global__ void k_pack_w(const float* __restrict__ W, unsigned short* __restrict__ Wp) {
    int p = blockIdx.x * blockDim.x + threadIdx.x;
    if (p >= C * C) return;
    int j = p & 7;
    int l = (p >> 3) & 63;
    int t = p >> 9;           // ct*4 + ks
    int ks = t & 3, ct = t >> 2;
    int k = ks * 32 + ((l >> 4) << 3) + j;
    int c = (ct << 4) + (l & 15);
    Wp[p] = f2b(W[k * C + c]);
}

// ---------------- MFMA GEMM: H[n,128] = bf16(X[n,128]) @ Wp ----------------
__global__ __launch_bounds__(256) void k_gemm_mfma(
    const float* __restrict__ X, const unsigned short* __restrict__ Wp,
    float* __restrict__ H, int n) {
    __shared__ unsigned short xs[32 * C];  // 8 KB, XOR-swizzled
    const int tid = threadIdx.x;
    const int base = blockIdx.x * 32;

    const float4* Xv = (const float4*)(X + (size_t)base * C);
    #pragma unroll
    for (int i = 0; i < 4; ++i) {
        int idx4 = i * 256 + tid;
        int elem = idx4 * 4;
        int r = elem >> 7, c = elem & 127;
        float4 v = make_float4(0.f, 0.f, 0.f, 0.f);
        if (base + r < n) v = Xv[idx4];
        ushort4_t pkt;
        pkt.x = f2b(v.x); pkt.y = f2b(v.y); pkt.z = f2b(v.z); pkt.w = f2b(v.w);
        int byte = (r * 256 + c * 2) ^ ((r & 7) << 4);
        *(ushort4_t*)((char*)xs + byte) = pkt;
    }
    __syncthreads();

    const int lane = tid & 63;
    const int wid = tid >> 6;
    const int wm = wid >> 1;
    const int wn = wid & 1;
    const int arow = wm * 16 + (lane & 15);
    const int kg = lane >> 4;

    f32x4 acc[4] = {f32x4{0,0,0,0}, f32x4{0,0,0,0}, f32x4{0,0,0,0}, f32x4{0,0,0,0}};

    #pragma unroll
    for (int ks = 0; ks < 4; ++ks) {
        int abyte = (arow * 256 + ks * 64 + kg * 16) ^ ((arow & 7) << 4);
        short8 a = *(const short8*)((const char*)xs + abyte);
        #pragma unroll
        for (int nt = 0; nt < 4; ++nt) {
            int ct = wn * 4 + nt;
            short8 b = *(const short8*)(Wp + (size_t)((ct * 4 + ks) * 64 + lane) * 8);
            acc[nt] = __builtin_amdgcn_mfma_f32_16x16x32_bf16(a, b, acc[nt], 0, 0, 0);
        }
    }

    const int rbase = base + wm * 16 + kg * 4;
    #pragma unroll
    for (int nt = 0; nt < 4; ++nt) {
        int col = wn * 64 + nt * 16 + (lane & 15);
        #pragma unroll
        for (int r = 0; r < 4; ++r) {
            int row = rbase + r;
            if (row >= n) continue;
            H[(size_t)row * C + col] = acc[nt][r];
        }
    }
}

// ---------------- fused aggregate + bias + LayerNorm + GELU (+residual) ----------------
// one 64-lane wave per dst row; gathers CSR edges, accumulates in regs, writes once.
__global__ __launch_bounds__(256) void k_agg_ln_gelu(
    const int* __restrict__ rowbeg, const int* __restrict__ rowend,
    const int* __restrict__ esrc, const float* __restrict__ ews,
    const float* __restrict__ H, const float* __restrict__ dis,
    const float* __restrict__ bias, const float* __restrict__ g,
    const float* __restrict__ beta, const float* __restrict__ resid,
    float* __restrict__ Out, int n) {
    int row = blockIdx.x * 4 + (threadIdx.x >> 6);
    if (row >= n) return;
    int lane = threadIdx.x & 63;

    float d = dis[row];
    const float* hrow = H + (size_t)row * C;
    float a0 = d * d * hrow[lane];
    float a1 = d * d * hrow[lane + 64];

    int ei = rowbeg[row];
    const int eend = rowend[row];
    for (; ei + 1 < eend; ei += 2) {
        int s0 = esrc[ei], s1 = esrc[ei + 1];
        float w0 = ews[ei], w1 = ews[ei + 1];
        const float* h0 = H + (size_t)s0 * C;
        const float* h1 = H + (size_t)s1 * C;
        float v00 = h0[lane], v01 = h0[lane + 64];
        float v10 = h1[lane], v11 = h1[lane + 64];
        a0 += w0 * v00 + w1 * v10;
        a1 += w0 * v01 + w1 * v11;
    }
    if (ei < eend) {
        int s0 = esrc[ei];
        float w0 = ews[ei];
        a0 += w0 * H[(size_t)s0 * C + lane];
        a1 += w0 * H[(size_t)s0 * C + lane + 64];
    }

    a0 += bias[lane];
    a1 += bias[lane + 64];

    // LayerNorm over 128 cols (2 per lane)
    float s = a0 + a1;
    float sq = a0 * a0 + a1 * a1;
    #pragma unroll
    for (int off = 32; off >= 1; off >>= 1) {
        s  += __shfl_xor(s, off, 64);
        sq += __shfl_xor(sq, off, 64);
    }
    float mu = s * (1.0f / C);
    float var = sq * (1.0f / C) - mu * mu;
    float rstd = rsqrtf(var + 1e-5f);

    float t0 = (a0 - mu) * rstd * g[lane] + beta[lane];
    float t1 = (a1 - mu) * rstd * g[lane + 64] + beta[lane + 64];
    t0 = 0.5f * t0 * (1.0f + erff(t0 * 0.70710678118654752f));
    t1 = 0.5f * t1 * (1.0f + erff(t1 * 0.70710678118654752f));

    if (resid != nullptr) {
        t0 += resid[(size_t)row * C + lane];
        t1 += resid[(size_t)row * C + lane + 64];
    }
    float* orow = Out + (size_t)row * C;
    orow[lane] = t0;
    orow[lane + 64] = t1;
}

// ---------------- launch ----------------

extern "C" void kernel_launch(void* const* d_in, const int* in_sizes, int n_in,
                              void* d_out, int out_size, void* d_ws, size_t ws_size,
                              hipStream_t stream) {
    const float* x      = (const float*)d_in[0];
    const int*   eidx   = (const int*)d_in[1];
    const float* ew     = (const float*)d_in[2];
    const float* W1     = (const float*)d_in[3];
    const float* b1     = (const float*)d_in[4];
    const float* g1     = (const float*)d_in[5];
    const float* beta1  = (const float*)d_in[6];
    const float* W2     = (const float*)d_in[7];
    const float* b2     = (const float*)d_in[8];
    const float* g2     = (const float*)d_in[9];
    const float* beta2  = (const float*)d_in[10];

    const int n = in_sizes[0] / C;
    const int e = in_sizes[2];
    const int* src = eidx;
    const int* dst = eidx + e;

    float* out = (float*)d_out;

    // workspace layout
    float* dis    = (float*)d_ws;                 // n
    int*   cnt    = (int*)(dis + n);              // n
    int*   rowbeg = cnt + n;                      // n
    int*   rowcur = rowbeg + n;                   // n  (becomes rowend after k_place)
    int*   esrc   = rowcur + n;                   // e
    float* ews    = (float*)(esrc + e);           // e
    int*   cursor = (int*)(ews + e);              // 1
    float* buf1   = (float*)(cursor + 1);         // n*C
    unsigned short* W1p = (unsigned short*)(buf1 + (size_t)n * C);  // C*C u16
    unsigned short* W2p = W1p + C * C;

    const int B = 256;
    const int gn = (n + B - 1) / B;
    const int ge = (e + B - 1) / B;

    // gcn_norm + CSR
    k_zero<<<gn, B, 0, stream>>>(cnt, cursor, n);
    k_cnt<<<ge, B, 0, stream>>>(dst, cnt, e);
    k_finalize_dis<<<gn, B, 0, stream>>>(cnt, dis, n);
    k_reserve<<<gn, B, 0, stream>>>(cnt, rowbeg, rowcur, cursor, n);
    k_place<<<ge, B, 0, stream>>>(src, dst, ew, dis, rowcur, esrc, ews, e);

    // pack weights
    k_pack_w<<<(C * C + B - 1) / B, B, 0, stream>>>(W1, W1p);
    k_pack_w<<<(C * C + B - 1) / B, B, 0, stream>>>(W2, W2p);

    // ---- layer 1 ----
    k_gemm_mfma<<<(n + 31) / 32, B, 0, stream>>>(x, W1p, buf1, n);
    k_agg_ln_gelu<<<(n + 3) / 4, B, 0, stream>>>(rowbeg, rowcur, esrc, ews, buf1,
                                                 dis, b1, g1, beta1, nullptr, out, n);

    // ---- layer 2 ----
    k_gemm_mfma<<<(n + 31) / 32, B, 0, stream>>>(out, W2p, buf1, n);
    k_agg_ln_gelu<<<(n + 3) / 4, B, 0, stream>>>(rowbeg, rowcur, esrc, ews, buf1,
                                                 dis, b2, g2, beta2, x, out, n);
}

// Round 4
// 240.422 us; speedup vs baseline: 3.8703x; 1.1246x over previous
//
#include <hip/hip_runtime.h>
#include <math.h>

#define C 128

typedef __attribute__((ext_vector_type(8))) short short8;
typedef __attribute__((ext_vector_type(4))) float f32x4;
typedef __attribute__((ext_vector_type(4))) unsigned short ushort4_t;

__device__ inline unsigned short f2b(float f) {
    union { float f; unsigned int u; } v; v.f = f;
    unsigned int u = v.u;
    return (unsigned short)((u + 0x7FFFu + ((u >> 16) & 1u)) >> 16);  // RNE
}
__device__ inline float bits2f(unsigned int u) {
    union { unsigned int u; float f; } v; v.u = u; return v.f;
}

// ---------------- gcn_norm + CSR build ----------------

__global__ void k_zero(int* __restrict__ cnt, int* __restrict__ cursor, int n) {
    int i = blockIdx.x * blockDim.x + threadIdx.x;
    if (i < n) cnt[i] = 0;
    if (i == 0) *cursor = 0;
}

__global__ void k_cnt(const int* __restrict__ dst, int* __restrict__ cnt, int e) {
    int i = blockIdx.x * blockDim.x + threadIdx.x;
    if (i < e) atomicAdd(&cnt[dst[i]], 1);
}

// dis = rsqrt(deg+1); reserve CSR segment
__global__ void k_dis_reserve(const int* __restrict__ cnt, float* __restrict__ dis,
                              int* __restrict__ rowbeg, int* __restrict__ rowcur,
                              int* __restrict__ cursor, int n) {
    int i = blockIdx.x * blockDim.x + threadIdx.x;
    if (i < n) {
        dis[i] = rsqrtf((float)cnt[i] + 1.0f);
        int b = atomicAdd(cursor, cnt[i]);
        rowbeg[i] = b;
        rowcur[i] = b;
    }
}

// place edge into its dst segment; edata = {src, bits(w_norm)}
__global__ void k_place(const int* __restrict__ src, const int* __restrict__ dst,
                        const float* __restrict__ ew, const float* __restrict__ dis,
                        int* __restrict__ rowcur, int2* __restrict__ edata, int e) {
    int i = blockIdx.x * blockDim.x + threadIdx.x;
    if (i >= e) return;
    int s = src[i], d = dst[i];
    int p = atomicAdd(&rowcur[d], 1);
    float w = dis[s] * ew[i] * dis[d];
    union { float f; int i; } wb; wb.f = w;
    edata[p] = make_int2(s, wb.i);
}

// ---------------- W pack: f32 [128][128] -> bf16 fragment layout ----------------
__global__ void k_pack_w(const float* __restrict__ W, unsigned short* __restrict__ Wp) {
    int p = blockIdx.x * blockDim.x + threadIdx.x;
    if (p >= C * C) return;
    int j = p & 7;
    int l = (p >> 3) & 63;
    int t = p >> 9;           // ct*4 + ks
    int ks = t & 3, ct = t >> 2;
    int k = ks * 32 + ((l >> 4) << 3) + j;
    int c = (ct << 4) + (l & 15);
    Wp[p] = f2b(W[k * C + c]);
}

// ---------------- MFMA GEMM: Hb[n,128](bf16) = bf16(X[n,128]) @ Wp ----------------
__global__ __launch_bounds__(256) void k_gemm_mfma(
    const float* __restrict__ X, const unsigned short* __restrict__ Wp,
    unsigned short* __restrict__ Hb, int n) {
    __shared__ unsigned short xs[32 * C];  // 8 KB, XOR-swizzled
    const int tid = threadIdx.x;
    const int base = blockIdx.x * 32;

    const float4* Xv = (const float4*)(X + (size_t)base * C);
    #pragma unroll
    for (int i = 0; i < 4; ++i) {
        int idx4 = i * 256 + tid;
        int elem = idx4 * 4;
        int r = elem >> 7, c = elem & 127;
        float4 v = make_float4(0.f, 0.f, 0.f, 0.f);
        if (base + r < n) v = Xv[idx4];
        ushort4_t pkt;
        pkt.x = f2b(v.x); pkt.y = f2b(v.y); pkt.z = f2b(v.z); pkt.w = f2b(v.w);
        int byte = (r * 256 + c * 2) ^ ((r & 7) << 4);
        *(ushort4_t*)((char*)xs + byte) = pkt;
    }
    __syncthreads();

    const int lane = tid & 63;
    const int wid = tid >> 6;
    const int wm = wid >> 1;
    const int wn = wid & 1;
    const int arow = wm * 16 + (lane & 15);
    const int kg = lane >> 4;

    f32x4 acc[4] = {f32x4{0,0,0,0}, f32x4{0,0,0,0}, f32x4{0,0,0,0}, f32x4{0,0,0,0}};

    #pragma unroll
    for (int ks = 0; ks < 4; ++ks) {
        int abyte = (arow * 256 + ks * 64 + kg * 16) ^ ((arow & 7) << 4);
        short8 a = *(const short8*)((const char*)xs + abyte);
        #pragma unroll
        for (int nt = 0; nt < 4; ++nt) {
            int ct = wn * 4 + nt;
            short8 b = *(const short8*)(Wp + (size_t)((ct * 4 + ks) * 64 + lane) * 8);
            acc[nt] = __builtin_amdgcn_mfma_f32_16x16x32_bf16(a, b, acc[nt], 0, 0, 0);
        }
    }

    const int rbase = base + wm * 16 + kg * 4;
    #pragma unroll
    for (int nt = 0; nt < 4; ++nt) {
        int col = wn * 64 + nt * 16 + (lane & 15);
        #pragma unroll
        for (int r = 0; r < 4; ++r) {
            int row = rbase + r;
            if (row >= n) continue;
            Hb[(size_t)row * C + col] = f2b(acc[nt][r]);
        }
    }
}

// ---------------- fused aggregate + bias + LayerNorm + GELU (+residual) ----------------
// one 64-lane wave per dst row; lane covers cols 2*lane, 2*lane+1 (one u32 of 2 bf16).
__global__ __launch_bounds__(256) void k_agg_ln_gelu(
    const int* __restrict__ rowbeg, const int* __restrict__ rowend,
    const int2* __restrict__ edata,
    const unsigned int* __restrict__ Hb32, const float* __restrict__ dis,
    const float* __restrict__ bias, const float* __restrict__ g,
    const float* __restrict__ beta, const float* __restrict__ resid,
    float* __restrict__ Out, int n) {
    int row = blockIdx.x * 4 + (threadIdx.x >> 6);
    if (row >= n) return;
    int lane = threadIdx.x & 63;

    float d = dis[row];
    unsigned int hu = Hb32[(size_t)row * 64 + lane];
    float a0 = d * d * bits2f(hu << 16);
    float a1 = d * d * bits2f(hu & 0xFFFF0000u);

    int ei = rowbeg[row];
    const int eend = rowend[row];
    for (; ei + 1 < eend; ei += 2) {
        int2 e0 = edata[ei], e1 = edata[ei + 1];
        float w0 = bits2f((unsigned int)e0.y);
        float w1 = bits2f((unsigned int)e1.y);
        unsigned int u0 = Hb32[(size_t)e0.x * 64 + lane];
        unsigned int u1 = Hb32[(size_t)e1.x * 64 + lane];
        a0 += w0 * bits2f(u0 << 16) + w1 * bits2f(u1 << 16);
        a1 += w0 * bits2f(u0 & 0xFFFF0000u) + w1 * bits2f(u1 & 0xFFFF0000u);
    }
    if (ei < eend) {
        int2 e0 = edata[ei];
        float w0 = bits2f((unsigned int)e0.y);
        unsigned int u0 = Hb32[(size_t)e0.x * 64 + lane];
        a0 += w0 * bits2f(u0 << 16);
        a1 += w0 * bits2f(u0 & 0xFFFF0000u);
    }

    int c0 = lane * 2;
    a0 += bias[c0];
    a1 += bias[c0 + 1];

    // LayerNorm over 128 cols (2 per lane)
    float s = a0 + a1;
    float sq = a0 * a0 + a1 * a1;
    #pragma unroll
    for (int off = 32; off >= 1; off >>= 1) {
        s  += __shfl_xor(s, off, 64);
        sq += __shfl_xor(sq, off, 64);
    }
    float mu = s * (1.0f / C);
    float var = sq * (1.0f / C) - mu * mu;
    float rstd = rsqrtf(var + 1e-5f);

    float t0 = (a0 - mu) * rstd * g[c0] + beta[c0];
    float t1 = (a1 - mu) * rstd * g[c0 + 1] + beta[c0 + 1];
    t0 = 0.5f * t0 * (1.0f + erff(t0 * 0.70710678118654752f));
    t1 = 0.5f * t1 * (1.0f + erff(t1 * 0.70710678118654752f));

    if (resid != nullptr) {
        float2 rv = *(const float2*)(resid + (size_t)row * C + c0);
        t0 += rv.x;
        t1 += rv.y;
    }
    *(float2*)(Out + (size_t)row * C + c0) = make_float2(t0, t1);
}

// ---------------- launch ----------------

extern "C" void kernel_launch(void* const* d_in, const int* in_sizes, int n_in,
                              void* d_out, int out_size, void* d_ws, size_t ws_size,
                              hipStream_t stream) {
    const float* x      = (const float*)d_in[0];
    const int*   eidx   = (const int*)d_in[1];
    const float* ew     = (const float*)d_in[2];
    const float* W1     = (const float*)d_in[3];
    const float* b1     = (const float*)d_in[4];
    const float* g1     = (const float*)d_in[5];
    const float* beta1  = (const float*)d_in[6];
    const float* W2     = (const float*)d_in[7];
    const float* b2     = (const float*)d_in[8];
    const float* g2     = (const float*)d_in[9];
    const float* beta2  = (const float*)d_in[10];

    const int n = in_sizes[0] / C;
    const int e = in_sizes[2];
    const int* src = eidx;
    const int* dst = eidx + e;

    float* out = (float*)d_out;

    // workspace layout
    float* dis    = (float*)d_ws;                 // n
    int*   cnt    = (int*)(dis + n);              // n
    int*   rowbeg = cnt + n;                      // n
    int*   rowcur = rowbeg + n;                   // n  (becomes rowend after k_place)
    int2*  edata  = (int2*)(rowcur + n);          // e int2
    int*   cursor = (int*)(edata + e);            // 1
    unsigned short* Hb = (unsigned short*)(cursor + 1);             // n*C bf16
    unsigned short* W1p = Hb + (size_t)n * C;                       // C*C u16
    unsigned short* W2p = W1p + C * C;

    const int B = 256;
    const int gn = (n + B - 1) / B;
    const int ge = (e + B - 1) / B;

    // gcn_norm + CSR
    k_zero<<<gn, B, 0, stream>>>(cnt, cursor, n);
    k_cnt<<<ge, B, 0, stream>>>(dst, cnt, e);
    k_dis_reserve<<<gn, B, 0, stream>>>(cnt, dis, rowbeg, rowcur, cursor, n);
    k_place<<<ge, B, 0, stream>>>(src, dst, ew, dis, rowcur, edata, e);

    // pack weights
    k_pack_w<<<(C * C + B - 1) / B, B, 0, stream>>>(W1, W1p);
    k_pack_w<<<(C * C + B - 1) / B, B, 0, stream>>>(W2, W2p);

    // ---- layer 1 ----
    k_gemm_mfma<<<(n + 31) / 32, B, 0, stream>>>(x, W1p, Hb, n);
    k_agg_ln_gelu<<<(n + 3) / 4, B, 0, stream>>>(rowbeg, rowcur, edata,
                                                 (const unsigned int*)Hb, dis,
                                                 b1, g1, beta1, nullptr, out, n);

    // ---- layer 2 ----
    k_gemm_mfma<<<(n + 31) / 32, B, 0, stream>>>(out, W2p, Hb, n);
    k_agg_ln_gelu<<<(n + 3) / 4, B, 0, stream>>>(rowbeg, rowcur, edata,
                                                 (const unsigned int*)Hb, dis,
                                                 b2, g2, beta2, x, out, n);
}